// Round 2
// baseline (271.950 us; speedup 1.0000x reference)
//
#include <hip/hip_runtime.h>
#include <math.h>

#define TSIZE (1u << 20)
#define PRIME_Y 2654435761u

__global__ __launch_bounds__(256) void hashsiren_kernel(
    const float* __restrict__ coords,
    const float* __restrict__ table,
    const float* __restrict__ W0, const float* __restrict__ b0,
    const float* __restrict__ W1, const float* __restrict__ b1,
    const float* __restrict__ W2, const float* __restrict__ b2,
    const float* __restrict__ W3, const float* __restrict__ b3,
    float* __restrict__ out, int N)
{
    __shared__ float sW0[384];
    __shared__ float sW1[256];
    __shared__ float sW2[256];
    __shared__ float sb0[16], sb1[16], sb2[16], sW3[16];
    __shared__ float sb3;

    const int t = threadIdx.x;
    for (int i = t; i < 384; i += 256) sW0[i] = W0[i];
    sW1[t] = W1[t];
    sW2[t] = W2[t];
    if (t < 16) { sb0[t] = b0[t]; sb1[t] = b1[t]; sb2[t] = b2[t]; sW3[t] = W3[t]; }
    if (t == 0) sb3 = b3[0];
    __syncthreads();

    const int idx = blockIdx.x * 256 + t;
    if (idx >= N) return;

    const float2 c = reinterpret_cast<const float2*>(coords)[idx];

    // ---- hashed levels 6..11: compute all 24 gather addresses, issue ALL loads
    // up front so they stay in flight while we do the dense levels.
    float2 hv00[6], hv10[6], hv01[6], hv11[6];
    float hwx[6], hwy[6];
    #pragma unroll
    for (int l = 0; l < 6; ++l) {
        const int res = 16 << (l + 6);
        const float px = c.x * (float)res;
        const float py = c.y * (float)res;
        const float fx = floorf(px), fy = floorf(py);
        hwx[l] = px - fx;
        hwy[l] = py - fy;
        const unsigned ux = (unsigned)(int)fx, uy = (unsigned)(int)fy;
        const unsigned hy0 = uy * PRIME_Y;
        const unsigned hy1 = (uy + 1u) * PRIME_Y;
        const float2* __restrict__ tl =
            reinterpret_cast<const float2*>(table) + (size_t)(l + 6) * TSIZE;
        hv00[l] = tl[(ux ^ hy0) & (TSIZE - 1u)];
        hv10[l] = tl[((ux + 1u) ^ hy0) & (TSIZE - 1u)];
        hv01[l] = tl[(ux ^ hy1) & (TSIZE - 1u)];
        hv11[l] = tl[((ux + 1u) ^ hy1) & (TSIZE - 1u)];
    }

    float enc[24];
    // ---- dense levels 0..5 (tables total ~2.8 MB, cache-resident) overlap
    // with the in-flight hashed gathers.
    #pragma unroll
    for (int lvl = 0; lvl < 6; ++lvl) {
        const int res = 16 << lvl;
        const float px = c.x * (float)res;
        const float py = c.y * (float)res;
        const float fx = floorf(px), fy = floorf(py);
        const float wx = px - fx, wy = py - fy;
        const int ix = (int)fx, iy = (int)fy;
        const int stride = res + 1;
        const int base = ix + iy * stride;
        const float2* __restrict__ tl =
            reinterpret_cast<const float2*>(table) + (size_t)lvl * TSIZE;
        const float2 v00 = tl[base];
        const float2 v10 = tl[base + 1];
        const float2 v01 = tl[base + stride];
        const float2 v11 = tl[base + stride + 1];
        const float w00 = (1.0f - wx) * (1.0f - wy);
        const float w10 = wx * (1.0f - wy);
        const float w01 = (1.0f - wx) * wy;
        const float w11 = wx * wy;
        enc[2 * lvl]     = v00.x * w00 + v10.x * w10 + v01.x * w01 + v11.x * w11;
        enc[2 * lvl + 1] = v00.y * w00 + v10.y * w10 + v01.y * w01 + v11.y * w11;
    }

    // ---- interpolate hashed levels (waitcnt drains in issue order)
    #pragma unroll
    for (int l = 0; l < 6; ++l) {
        const float wx = hwx[l], wy = hwy[l];
        const float w00 = (1.0f - wx) * (1.0f - wy);
        const float w10 = wx * (1.0f - wy);
        const float w01 = (1.0f - wx) * wy;
        const float w11 = wx * wy;
        enc[2 * (l + 6)]     = hv00[l].x * w00 + hv10[l].x * w10 + hv01[l].x * w01 + hv11[l].x * w11;
        enc[2 * (l + 6) + 1] = hv00[l].y * w00 + hv10[l].y * w10 + hv01[l].y * w01 + hv11[l].y * w11;
    }

    // ---- MLP: sin(300*(enc@W0+b0)) -> sin(@W1+b1) -> sin(@W2+b2) -> @W3+b3
    float h0[16];
    #pragma unroll
    for (int j = 0; j < 16; ++j) {
        float a = sb0[j];
        #pragma unroll
        for (int k = 0; k < 24; ++k) a += enc[k] * sW0[k * 16 + j];
        h0[j] = __sinf(300.0f * a);
    }
    float h1[16];
    #pragma unroll
    for (int j = 0; j < 16; ++j) {
        float a = sb1[j];
        #pragma unroll
        for (int k = 0; k < 16; ++k) a += h0[k] * sW1[k * 16 + j];
        h1[j] = __sinf(a);
    }
    float h2[16];
    #pragma unroll
    for (int j = 0; j < 16; ++j) {
        float a = sb2[j];
        #pragma unroll
        for (int k = 0; k < 16; ++k) a += h1[k] * sW2[k * 16 + j];
        h2[j] = __sinf(a);
    }
    float o = sb3;
    #pragma unroll
    for (int k = 0; k < 16; ++k) o += h2[k] * sW3[k];
    out[idx] = o;
}

extern "C" void kernel_launch(void* const* d_in, const int* in_sizes, int n_in,
                              void* d_out, int out_size, void* d_ws, size_t ws_size,
                              hipStream_t stream) {
    const float* coords = (const float*)d_in[0];
    const float* table  = (const float*)d_in[1];
    const float* W0 = (const float*)d_in[2];
    const float* b0 = (const float*)d_in[3];
    const float* W1 = (const float*)d_in[4];
    const float* b1 = (const float*)d_in[5];
    const float* W2 = (const float*)d_in[6];
    const float* b2 = (const float*)d_in[7];
    const float* W3 = (const float*)d_in[8];
    const float* b3 = (const float*)d_in[9];
    float* out = (float*)d_out;

    const int N = in_sizes[0] / 2;  // coords is [N,2]
    const int block = 256;
    const int grid = (N + block - 1) / block;
    hashsiren_kernel<<<grid, block, 0, stream>>>(coords, table, W0, b0, W1, b1,
                                                 W2, b2, W3, b3, out, N);
}

// Round 3
// 197.681 us; speedup vs baseline: 1.3757x; 1.3757x over previous
//
#include <hip/hip_runtime.h>
#include <math.h>

#define TSIZE (1u << 20)
#define PRIME_Y 2654435761u
#define NHASH 6   // hashed levels 6..11

__device__ __forceinline__ unsigned pack_bf16x2(float a, float b) {
    unsigned ua = __float_as_uint(a);
    unsigned ub = __float_as_uint(b);
    ua = (ua + 0x7fffu + ((ua >> 16) & 1u)) >> 16;   // RNE
    ub = (ub + 0x7fffu + ((ub >> 16) & 1u)) >> 16;
    return (ua & 0xffffu) | (ub << 16);
}
__device__ __forceinline__ float2 unpack_bf16x2(unsigned u) {
    float2 r;
    r.x = __uint_as_float(u << 16);
    r.y = __uint_as_float(u & 0xffff0000u);
    return r;
}

// ---- pass 0: convert hashed-level tables (f32 float2) -> packed bf16x2 in ws
__global__ __launch_bounds__(256) void convert_kernel(const float* __restrict__ table,
                                                      unsigned* __restrict__ wtab) {
    const size_t total = (size_t)NHASH * TSIZE;
    const float2* __restrict__ src =
        reinterpret_cast<const float2*>(table) + (size_t)6 * TSIZE;
    for (size_t i = (size_t)blockIdx.x * 256 + threadIdx.x; i < total;
         i += (size_t)gridDim.x * 256) {
        float2 v = src[i];
        __builtin_nontemporal_store(pack_bf16x2(v.x, v.y), &wtab[i]);
    }
}

// ---- per-level gather pass: one hashed level, whole point set.
// Each level's bf16 table is 4 MiB == one XCD L2.
__global__ __launch_bounds__(256) void pass_kernel(const float* __restrict__ coords,
                                                   const unsigned* __restrict__ wtab,
                                                   unsigned* __restrict__ wenc,
                                                   int lvl, int N) {
    const int idx = blockIdx.x * 256 + threadIdx.x;
    if (idx >= N) return;
    const float2 c = reinterpret_cast<const float2*>(coords)[idx];
    const int res = 16 << (lvl + 6);
    const float px = c.x * (float)res;
    const float py = c.y * (float)res;
    const float fx = floorf(px), fy = floorf(py);
    const float wx = px - fx, wy = py - fy;
    const unsigned ux = (unsigned)(int)fx, uy = (unsigned)(int)fy;
    const unsigned hy0 = uy * PRIME_Y;
    const unsigned hy1 = (uy + 1u) * PRIME_Y;
    const unsigned* __restrict__ tl = wtab + (size_t)lvl * TSIZE;
    const unsigned u00 = tl[(ux ^ hy0) & (TSIZE - 1u)];
    const unsigned u10 = tl[((ux + 1u) ^ hy0) & (TSIZE - 1u)];
    const unsigned u01 = tl[(ux ^ hy1) & (TSIZE - 1u)];
    const unsigned u11 = tl[((ux + 1u) ^ hy1) & (TSIZE - 1u)];
    const float2 v00 = unpack_bf16x2(u00);
    const float2 v10 = unpack_bf16x2(u10);
    const float2 v01 = unpack_bf16x2(u01);
    const float2 v11 = unpack_bf16x2(u11);
    const float w00 = (1.0f - wx) * (1.0f - wy);
    const float w10 = wx * (1.0f - wy);
    const float w01 = (1.0f - wx) * wy;
    const float w11 = wx * wy;
    const float e0 = v00.x * w00 + v10.x * w10 + v01.x * w01 + v11.x * w11;
    const float e1 = v00.y * w00 + v10.y * w10 + v01.y * w01 + v11.y * w11;
    __builtin_nontemporal_store(pack_bf16x2(e0, e1), &wenc[(size_t)lvl * N + idx]);
}

// ---- final: dense levels 0..5 (f32, cache-hot) + hashed enc from ws + MLP
__global__ __launch_bounds__(256) void mlp_kernel(
    const float* __restrict__ coords,
    const float* __restrict__ table,
    const unsigned* __restrict__ wenc,
    const float* __restrict__ W0, const float* __restrict__ b0,
    const float* __restrict__ W1, const float* __restrict__ b1,
    const float* __restrict__ W2, const float* __restrict__ b2,
    const float* __restrict__ W3, const float* __restrict__ b3,
    float* __restrict__ out, int N)
{
    __shared__ float sW0[384];
    __shared__ float sW1[256];
    __shared__ float sW2[256];
    __shared__ float sb0[16], sb1[16], sb2[16], sW3[16];
    __shared__ float sb3;

    const int t = threadIdx.x;
    for (int i = t; i < 384; i += 256) sW0[i] = W0[i];
    sW1[t] = W1[t];
    sW2[t] = W2[t];
    if (t < 16) { sb0[t] = b0[t]; sb1[t] = b1[t]; sb2[t] = b2[t]; sW3[t] = W3[t]; }
    if (t == 0) sb3 = b3[0];
    __syncthreads();

    const int idx = blockIdx.x * 256 + t;
    if (idx >= N) return;

    // issue hashed-enc streaming loads first (read-once -> nontemporal)
    unsigned he[NHASH];
    #pragma unroll
    for (int l = 0; l < NHASH; ++l)
        he[l] = __builtin_nontemporal_load(&wenc[(size_t)l * N + idx]);

    const float2 c = reinterpret_cast<const float2*>(coords)[idx];

    float enc[24];
    #pragma unroll
    for (int lvl = 0; lvl < 6; ++lvl) {
        const int res = 16 << lvl;
        const float px = c.x * (float)res;
        const float py = c.y * (float)res;
        const float fx = floorf(px), fy = floorf(py);
        const float wx = px - fx, wy = py - fy;
        const int ix = (int)fx, iy = (int)fy;
        const int stride = res + 1;
        const int base = ix + iy * stride;
        const float2* __restrict__ tl =
            reinterpret_cast<const float2*>(table) + (size_t)lvl * TSIZE;
        const float2 v00 = tl[base];
        const float2 v10 = tl[base + 1];
        const float2 v01 = tl[base + stride];
        const float2 v11 = tl[base + stride + 1];
        const float w00 = (1.0f - wx) * (1.0f - wy);
        const float w10 = wx * (1.0f - wy);
        const float w01 = (1.0f - wx) * wy;
        const float w11 = wx * wy;
        enc[2 * lvl]     = v00.x * w00 + v10.x * w10 + v01.x * w01 + v11.x * w11;
        enc[2 * lvl + 1] = v00.y * w00 + v10.y * w10 + v01.y * w01 + v11.y * w11;
    }
    #pragma unroll
    for (int l = 0; l < NHASH; ++l) {
        const float2 v = unpack_bf16x2(he[l]);
        enc[12 + 2 * l]     = v.x;
        enc[12 + 2 * l + 1] = v.y;
    }

    float h0[16];
    #pragma unroll
    for (int j = 0; j < 16; ++j) {
        float a = sb0[j];
        #pragma unroll
        for (int k = 0; k < 24; ++k) a += enc[k] * sW0[k * 16 + j];
        h0[j] = __sinf(300.0f * a);
    }
    float h1[16];
    #pragma unroll
    for (int j = 0; j < 16; ++j) {
        float a = sb1[j];
        #pragma unroll
        for (int k = 0; k < 16; ++k) a += h0[k] * sW1[k * 16 + j];
        h1[j] = __sinf(a);
    }
    float h2[16];
    #pragma unroll
    for (int j = 0; j < 16; ++j) {
        float a = sb2[j];
        #pragma unroll
        for (int k = 0; k < 16; ++k) a += h1[k] * sW2[k * 16 + j];
        h2[j] = __sinf(a);
    }
    float o = sb3;
    #pragma unroll
    for (int k = 0; k < 16; ++k) o += h2[k] * sW3[k];
    out[idx] = o;
}

// ---- fallback: R1 fused kernel (known-good, 272 us) for small ws
__global__ __launch_bounds__(256) void hashsiren_fused(
    const float* __restrict__ coords,
    const float* __restrict__ table,
    const float* __restrict__ W0, const float* __restrict__ b0,
    const float* __restrict__ W1, const float* __restrict__ b1,
    const float* __restrict__ W2, const float* __restrict__ b2,
    const float* __restrict__ W3, const float* __restrict__ b3,
    float* __restrict__ out, int N)
{
    __shared__ float sW0[384];
    __shared__ float sW1[256];
    __shared__ float sW2[256];
    __shared__ float sb0[16], sb1[16], sb2[16], sW3[16];
    __shared__ float sb3;

    const int t = threadIdx.x;
    for (int i = t; i < 384; i += 256) sW0[i] = W0[i];
    sW1[t] = W1[t];
    sW2[t] = W2[t];
    if (t < 16) { sb0[t] = b0[t]; sb1[t] = b1[t]; sb2[t] = b2[t]; sW3[t] = W3[t]; }
    if (t == 0) sb3 = b3[0];
    __syncthreads();

    const int idx = blockIdx.x * 256 + t;
    if (idx >= N) return;

    const float2 c = reinterpret_cast<const float2*>(coords)[idx];

    float2 hv00[6], hv10[6], hv01[6], hv11[6];
    float hwx[6], hwy[6];
    #pragma unroll
    for (int l = 0; l < 6; ++l) {
        const int res = 16 << (l + 6);
        const float px = c.x * (float)res;
        const float py = c.y * (float)res;
        const float fx = floorf(px), fy = floorf(py);
        hwx[l] = px - fx;
        hwy[l] = py - fy;
        const unsigned ux = (unsigned)(int)fx, uy = (unsigned)(int)fy;
        const unsigned hy0 = uy * PRIME_Y;
        const unsigned hy1 = (uy + 1u) * PRIME_Y;
        const float2* __restrict__ tl =
            reinterpret_cast<const float2*>(table) + (size_t)(l + 6) * TSIZE;
        hv00[l] = tl[(ux ^ hy0) & (TSIZE - 1u)];
        hv10[l] = tl[((ux + 1u) ^ hy0) & (TSIZE - 1u)];
        hv01[l] = tl[(ux ^ hy1) & (TSIZE - 1u)];
        hv11[l] = tl[((ux + 1u) ^ hy1) & (TSIZE - 1u)];
    }

    float enc[24];
    #pragma unroll
    for (int lvl = 0; lvl < 6; ++lvl) {
        const int res = 16 << lvl;
        const float px = c.x * (float)res;
        const float py = c.y * (float)res;
        const float fx = floorf(px), fy = floorf(py);
        const float wx = px - fx, wy = py - fy;
        const int ix = (int)fx, iy = (int)fy;
        const int stride = res + 1;
        const int base = ix + iy * stride;
        const float2* __restrict__ tl =
            reinterpret_cast<const float2*>(table) + (size_t)lvl * TSIZE;
        const float2 v00 = tl[base];
        const float2 v10 = tl[base + 1];
        const float2 v01 = tl[base + stride];
        const float2 v11 = tl[base + stride + 1];
        const float w00 = (1.0f - wx) * (1.0f - wy);
        const float w10 = wx * (1.0f - wy);
        const float w01 = (1.0f - wx) * wy;
        const float w11 = wx * wy;
        enc[2 * lvl]     = v00.x * w00 + v10.x * w10 + v01.x * w01 + v11.x * w11;
        enc[2 * lvl + 1] = v00.y * w00 + v10.y * w10 + v01.y * w01 + v11.y * w11;
    }
    #pragma unroll
    for (int l = 0; l < 6; ++l) {
        const float wx = hwx[l], wy = hwy[l];
        const float w00 = (1.0f - wx) * (1.0f - wy);
        const float w10 = wx * (1.0f - wy);
        const float w01 = (1.0f - wx) * wy;
        const float w11 = wx * wy;
        enc[2 * (l + 6)]     = hv00[l].x * w00 + hv10[l].x * w10 + hv01[l].x * w01 + hv11[l].x * w11;
        enc[2 * (l + 6) + 1] = hv00[l].y * w00 + hv10[l].y * w10 + hv01[l].y * w01 + hv11[l].y * w11;
    }

    float h0[16];
    #pragma unroll
    for (int j = 0; j < 16; ++j) {
        float a = sb0[j];
        #pragma unroll
        for (int k = 0; k < 24; ++k) a += enc[k] * sW0[k * 16 + j];
        h0[j] = __sinf(300.0f * a);
    }
    float h1[16];
    #pragma unroll
    for (int j = 0; j < 16; ++j) {
        float a = sb1[j];
        #pragma unroll
        for (int k = 0; k < 16; ++k) a += h0[k] * sW1[k * 16 + j];
        h1[j] = __sinf(a);
    }
    float h2[16];
    #pragma unroll
    for (int j = 0; j < 16; ++j) {
        float a = sb2[j];
        #pragma unroll
        for (int k = 0; k < 16; ++k) a += h1[k] * sW2[k * 16 + j];
        h2[j] = __sinf(a);
    }
    float o = sb3;
    #pragma unroll
    for (int k = 0; k < 16; ++k) o += h2[k] * sW3[k];
    out[idx] = o;
}

extern "C" void kernel_launch(void* const* d_in, const int* in_sizes, int n_in,
                              void* d_out, int out_size, void* d_ws, size_t ws_size,
                              hipStream_t stream) {
    const float* coords = (const float*)d_in[0];
    const float* table  = (const float*)d_in[1];
    const float* W0 = (const float*)d_in[2];
    const float* b0 = (const float*)d_in[3];
    const float* W1 = (const float*)d_in[4];
    const float* b1 = (const float*)d_in[5];
    const float* W2 = (const float*)d_in[6];
    const float* b2 = (const float*)d_in[7];
    const float* W3 = (const float*)d_in[8];
    const float* b3 = (const float*)d_in[9];
    float* out = (float*)d_out;

    const int N = in_sizes[0] / 2;  // coords is [N,2]
    const int block = 256;
    const int grid = (N + block - 1) / block;

    const size_t need = (size_t)NHASH * TSIZE * 4u   // bf16 tables, 24 MiB
                      + (size_t)NHASH * (size_t)N * 4u;  // packed enc, 24 MiB
    if (ws_size >= need) {
        unsigned* wtab = (unsigned*)d_ws;
        unsigned* wenc = wtab + (size_t)NHASH * TSIZE;
        convert_kernel<<<4096, block, 0, stream>>>(table, wtab);
        for (int l = 0; l < NHASH; ++l)
            pass_kernel<<<grid, block, 0, stream>>>(coords, wtab, wenc, l, N);
        mlp_kernel<<<grid, block, 0, stream>>>(coords, table, wenc,
                                               W0, b0, W1, b1, W2, b2, W3, b3,
                                               out, N);
    } else {
        hashsiren_fused<<<grid, block, 0, stream>>>(coords, table,
                                                    W0, b0, W1, b1, W2, b2, W3, b3,
                                                    out, N);
    }
}

// Round 4
// 187.857 us; speedup vs baseline: 1.4476x; 1.0523x over previous
//
#include <hip/hip_runtime.h>
#include <math.h>

#define TSIZE (1u << 20)
#define PRIME_Y 2654435761u
#define NHASH 6   // hashed levels 6..11

typedef __attribute__((ext_vector_type(8))) short short8;     // bf16x8 MFMA frag
typedef __attribute__((ext_vector_type(4))) float f32x4;      // MFMA acc frag
typedef __attribute__((ext_vector_type(4))) float float4v;
typedef __attribute__((ext_vector_type(4))) unsigned uint4v;
typedef __attribute__((ext_vector_type(2))) unsigned uint2v;

__device__ __forceinline__ unsigned bf16rne(unsigned u) {
    return (u + 0x7fffu + ((u >> 16) & 1u)) >> 16;   // RNE to bf16 (in low 16)
}
__device__ __forceinline__ unsigned pack_bf16x2(float a, float b) {
    return (bf16rne(__float_as_uint(a)) & 0xffffu) | (bf16rne(__float_as_uint(b)) << 16);
}
__device__ __forceinline__ float2 unpack_bf16x2(unsigned u) {
    float2 r;
    r.x = __uint_as_float(u << 16);
    r.y = __uint_as_float(u & 0xffff0000u);
    return r;
}
__device__ __forceinline__ short f2bf(float x) {
    return (short)(bf16rne(__float_as_uint(x)) & 0xffffu);
}
__device__ __forceinline__ float bf2f(short h) {
    return __uint_as_float(((unsigned)(unsigned short)h) << 16);
}

// ---- pass 0: convert hashed-level tables (f32 float2) -> packed bf16x2 in ws
__global__ __launch_bounds__(256) void convert_kernel(const float* __restrict__ table,
                                                      unsigned* __restrict__ wtab) {
    const size_t total4 = (size_t)NHASH * TSIZE / 2;   // float4 chunks (2 entries)
    const float4v* __restrict__ src =
        reinterpret_cast<const float4v*>(table + (size_t)6 * TSIZE * 2);
    uint2v* __restrict__ dst = reinterpret_cast<uint2v*>(wtab);
    for (size_t i = (size_t)blockIdx.x * 256 + threadIdx.x; i < total4;
         i += (size_t)gridDim.x * 256) {
        float4v v = __builtin_nontemporal_load(&src[i]);
        uint2v o;
        o.x = pack_bf16x2(v.x, v.y);
        o.y = pack_bf16x2(v.z, v.w);
        __builtin_nontemporal_store(o, &dst[i]);
    }
}

// ---- per-level gather pass: one hashed level, whole point set.
__global__ __launch_bounds__(256) void pass_kernel(const float* __restrict__ coords,
                                                   const unsigned* __restrict__ wtab,
                                                   unsigned* __restrict__ wenc,
                                                   int lvl, int N) {
    const int idx = blockIdx.x * 256 + threadIdx.x;
    if (idx >= N) return;
    const float2 c = reinterpret_cast<const float2*>(coords)[idx];
    const int res = 16 << (lvl + 6);
    const float px = c.x * (float)res;
    const float py = c.y * (float)res;
    const float fx = floorf(px), fy = floorf(py);
    const float wx = px - fx, wy = py - fy;
    const unsigned ux = (unsigned)(int)fx, uy = (unsigned)(int)fy;
    const unsigned hy0 = uy * PRIME_Y;
    const unsigned hy1 = (uy + 1u) * PRIME_Y;
    const unsigned* __restrict__ tl = wtab + (size_t)lvl * TSIZE;
    const unsigned u00 = tl[(ux ^ hy0) & (TSIZE - 1u)];
    const unsigned u10 = tl[((ux + 1u) ^ hy0) & (TSIZE - 1u)];
    const unsigned u01 = tl[(ux ^ hy1) & (TSIZE - 1u)];
    const unsigned u11 = tl[((ux + 1u) ^ hy1) & (TSIZE - 1u)];
    const float2 v00 = unpack_bf16x2(u00);
    const float2 v10 = unpack_bf16x2(u10);
    const float2 v01 = unpack_bf16x2(u01);
    const float2 v11 = unpack_bf16x2(u11);
    const float w00 = (1.0f - wx) * (1.0f - wy);
    const float w10 = wx * (1.0f - wy);
    const float w01 = (1.0f - wx) * wy;
    const float w11 = wx * wy;
    const float e0 = v00.x * w00 + v10.x * w10 + v01.x * w01 + v11.x * w11;
    const float e1 = v00.y * w00 + v10.y * w10 + v01.y * w01 + v11.y * w11;
    __builtin_nontemporal_store(pack_bf16x2(e0, e1), &wenc[(size_t)lvl * N + idx]);
}

// ---- final: dense levels + hashed enc from ws + MFMA SIREN MLP
// Per wave: 64 points. A-frag row=lane&15, k=(lane>>4)*8+j; B-frag col=lane&15;
// D: col=lane&15, row=(lane>>4)*4+reg (m89-verified).
// h-activations + W1/W2 are split bf16 hi+lo (2 MFMAs) to keep absmax ~2e-3.
__global__ __launch_bounds__(256) void mlp_kernel(
    const float* __restrict__ coords,
    const float* __restrict__ table,
    const unsigned* __restrict__ wenc,
    const float* __restrict__ W0, const float* __restrict__ b0,
    const float* __restrict__ W1, const float* __restrict__ b1,
    const float* __restrict__ W2, const float* __restrict__ b2,
    const float* __restrict__ W3, const float* __restrict__ b3,
    float* __restrict__ out, int N)
{
    __shared__ uint4v smem[1280];           // 4 waves * 64 rows * 80 B = 20480
    const int t = threadIdx.x;
    const int lane = t & 63;
    const int wv = t >> 6;
    const int n = lane & 15;                // B/D col; also A row (lane&15)
    const int kb = lane >> 4;               // k-block / D row group
    char* ldsw = (char*)smem + wv * 5120;   // per-wave region, 64 rows x 80 B

    // ---- B fragments (weights), loaded once. W1/W2 as hi+lo bf16 pairs.
    short8 bf0, b1a, b1b, b2a, b2b;
    #pragma unroll
    for (int j = 0; j < 8; ++j) {
        const int k = kb * 8 + j;
        bf0[j] = (k < 24) ? f2bf(W0[k * 16 + n]) : (short)0;
        const int k16 = k & 15;
        const float w1 = W1[k16 * 16 + n];
        const float w2 = W2[k16 * 16 + n];
        const short w1h = f2bf(w1), w2h = f2bf(w2);
        b1a[j] = w1h;                        // Whi stacked twice (k and k+16)
        b2a[j] = w2h;
        b1b[j] = (k < 16) ? f2bf(w1 - bf2f(w1h)) : (short)0;  // Wlo | 0
        b2b[j] = (k < 16) ? f2bf(w2 - bf2f(w2h)) : (short)0;
    }
    const float b0n = b0[n], b1n = b1[n], b2n = b2[n];
    const float w3n = W3[n];
    const float b3s = b3[0];

    const int idx = blockIdx.x * 256 + t;
    const int idxc = (idx < N) ? idx : (N - 1);

    // hashed-enc streaming loads first (stay in flight over dense interp)
    unsigned he[NHASH];
    #pragma unroll
    for (int l = 0; l < NHASH; ++l)
        he[l] = __builtin_nontemporal_load(&wenc[(size_t)l * N + idxc]);

    const float2 c = reinterpret_cast<const float2*>(coords)[idxc];

    float enc[24];
    #pragma unroll
    for (int lvl = 0; lvl < 6; ++lvl) {
        const int res = 16 << lvl;
        const float px = c.x * (float)res;
        const float py = c.y * (float)res;
        const float fx = floorf(px), fy = floorf(py);
        const float wx = px - fx, wy = py - fy;
        const int ix = (int)fx, iy = (int)fy;
        const int stride = res + 1;
        const int base = ix + iy * stride;
        const float2* __restrict__ tl =
            reinterpret_cast<const float2*>(table) + (size_t)lvl * TSIZE;
        const float2 v00 = tl[base];
        const float2 v10 = tl[base + 1];
        const float2 v01 = tl[base + stride];
        const float2 v11 = tl[base + stride + 1];
        const float w00 = (1.0f - wx) * (1.0f - wy);
        const float w10 = wx * (1.0f - wy);
        const float w01 = (1.0f - wx) * wy;
        const float w11 = wx * wy;
        enc[2 * lvl]     = v00.x * w00 + v10.x * w10 + v01.x * w01 + v11.x * w11;
        enc[2 * lvl + 1] = v00.y * w00 + v10.y * w10 + v01.y * w01 + v11.y * w11;
    }
    #pragma unroll
    for (int l = 0; l < NHASH; ++l) {
        const float2 v = unpack_bf16x2(he[l]);
        enc[12 + 2 * l]     = v.x;
        enc[12 + 2 * l + 1] = v.y;
    }

    // ---- stage enc as bf16, K padded 24->32, row = lane (80 B stride)
    unsigned u[12];
    #pragma unroll
    for (int k = 0; k < 12; ++k) u[k] = pack_bf16x2(enc[2 * k], enc[2 * k + 1]);
    {
        uint4v* rowp = (uint4v*)(ldsw + lane * 80);
        uint4v r0; r0.x = u[0]; r0.y = u[1]; r0.z = u[2]; r0.w = u[3];
        uint4v r1; r1.x = u[4]; r1.y = u[5]; r1.z = u[6]; r1.w = u[7];
        uint4v r2; r2.x = u[8]; r2.y = u[9]; r2.z = u[10]; r2.w = u[11];
        uint4v r3; r3.x = 0u; r3.y = 0u; r3.z = 0u; r3.w = 0u;
        rowp[0] = r0; rowp[1] = r1; rowp[2] = r2; rowp[3] = r3;
    }
    __syncthreads();

    short8 a[4];
    #pragma unroll
    for (int m = 0; m < 4; ++m)
        a[m] = *(const short8*)(ldsw + (m * 16 + n) * 80 + kb * 16);
    __syncthreads();

    const f32x4 z = {0.f, 0.f, 0.f, 0.f};
    f32x4 acc[4];
    #pragma unroll
    for (int m = 0; m < 4; ++m)
        acc[m] = __builtin_amdgcn_mfma_f32_16x16x32_bf16(a[m], bf0, z, 0, 0, 0);

    short* hp = (short*)ldsw;   // rows of 40 shorts: [0..15]=hi, [16..31]=lo

    // ---- layer 1: h0 = sin(300*(acc+b0)); stage hi|lo; mfma with W1 hi+lo
    #pragma unroll
    for (int m = 0; m < 4; ++m) {
        #pragma unroll
        for (int r = 0; r < 4; ++r) {
            const float v = __sinf(300.0f * (acc[m][r] + b0n));
            const short hi = f2bf(v);
            const short lo = f2bf(v - bf2f(hi));
            const int row = m * 16 + kb * 4 + r;
            hp[row * 40 + n] = hi;
            hp[row * 40 + 16 + n] = lo;
        }
    }
    __syncthreads();
    #pragma unroll
    for (int m = 0; m < 4; ++m)
        a[m] = *(const short8*)(ldsw + (m * 16 + n) * 80 + kb * 16);
    __syncthreads();
    #pragma unroll
    for (int m = 0; m < 4; ++m) {
        f32x4 p = __builtin_amdgcn_mfma_f32_16x16x32_bf16(a[m], b1a, z, 0, 0, 0);
        acc[m] = __builtin_amdgcn_mfma_f32_16x16x32_bf16(a[m], b1b, p, 0, 0, 0);
    }

    // ---- layer 2
    #pragma unroll
    for (int m = 0; m < 4; ++m) {
        #pragma unroll
        for (int r = 0; r < 4; ++r) {
            const float v = __sinf(acc[m][r] + b1n);
            const short hi = f2bf(v);
            const short lo = f2bf(v - bf2f(hi));
            const int row = m * 16 + kb * 4 + r;
            hp[row * 40 + n] = hi;
            hp[row * 40 + 16 + n] = lo;
        }
    }
    __syncthreads();
    #pragma unroll
    for (int m = 0; m < 4; ++m)
        a[m] = *(const short8*)(ldsw + (m * 16 + n) * 80 + kb * 16);
    __syncthreads();
    #pragma unroll
    for (int m = 0; m < 4; ++m) {
        f32x4 p = __builtin_amdgcn_mfma_f32_16x16x32_bf16(a[m], b2a, z, 0, 0, 0);
        acc[m] = __builtin_amdgcn_mfma_f32_16x16x32_bf16(a[m], b2b, p, 0, 0, 0);
    }

    // ---- layer 3 (final, 16->1) in f32: h2 = sin(acc+b2); o = h2@W3 + b3
    float red[4][4];
    #pragma unroll
    for (int m = 0; m < 4; ++m) {
        #pragma unroll
        for (int r = 0; r < 4; ++r) {
            float v = __sinf(acc[m][r] + b2n) * w3n;
            v += __shfl_xor(v, 1);
            v += __shfl_xor(v, 2);
            v += __shfl_xor(v, 4);
            v += __shfl_xor(v, 8);
            red[m][r] = v;     // identical across the 16 lanes of group kb
        }
    }
    const int m2 = n >> 2, r2 = n & 3;
    float ov = 0.f;
    #pragma unroll
    for (int m = 0; m < 4; ++m) {
        #pragma unroll
        for (int r = 0; r < 4; ++r)
            if (m == m2 && r == r2) ov = red[m][r];   // static idx -> cndmask
    }
    const int gidx = blockIdx.x * 256 + wv * 64 + m2 * 16 + kb * 4 + r2;
    if (gidx < N) out[gidx] = ov + b3s;
}

// ---- fallback: R1 fused kernel (known-good) for small ws
__global__ __launch_bounds__(256) void hashsiren_fused(
    const float* __restrict__ coords,
    const float* __restrict__ table,
    const float* __restrict__ W0, const float* __restrict__ b0,
    const float* __restrict__ W1, const float* __restrict__ b1,
    const float* __restrict__ W2, const float* __restrict__ b2,
    const float* __restrict__ W3, const float* __restrict__ b3,
    float* __restrict__ out, int N)
{
    __shared__ float sW0[384];
    __shared__ float sW1[256];
    __shared__ float sW2[256];
    __shared__ float sb0[16], sb1[16], sb2[16], sW3[16];
    __shared__ float sb3;

    const int t = threadIdx.x;
    for (int i = t; i < 384; i += 256) sW0[i] = W0[i];
    sW1[t] = W1[t];
    sW2[t] = W2[t];
    if (t < 16) { sb0[t] = b0[t]; sb1[t] = b1[t]; sb2[t] = b2[t]; sW3[t] = W3[t]; }
    if (t == 0) sb3 = b3[0];
    __syncthreads();

    const int idx = blockIdx.x * 256 + t;
    if (idx >= N) return;

    const float2 c = reinterpret_cast<const float2*>(coords)[idx];

    float2 hv00[6], hv10[6], hv01[6], hv11[6];
    float hwx[6], hwy[6];
    #pragma unroll
    for (int l = 0; l < 6; ++l) {
        const int res = 16 << (l + 6);
        const float px = c.x * (float)res;
        const float py = c.y * (float)res;
        const float fx = floorf(px), fy = floorf(py);
        hwx[l] = px - fx;
        hwy[l] = py - fy;
        const unsigned ux = (unsigned)(int)fx, uy = (unsigned)(int)fy;
        const unsigned hy0 = uy * PRIME_Y;
        const unsigned hy1 = (uy + 1u) * PRIME_Y;
        const float2* __restrict__ tl =
            reinterpret_cast<const float2*>(table) + (size_t)(l + 6) * TSIZE;
        hv00[l] = tl[(ux ^ hy0) & (TSIZE - 1u)];
        hv10[l] = tl[((ux + 1u) ^ hy0) & (TSIZE - 1u)];
        hv01[l] = tl[(ux ^ hy1) & (TSIZE - 1u)];
        hv11[l] = tl[((ux + 1u) ^ hy1) & (TSIZE - 1u)];
    }

    float enc[24];
    #pragma unroll
    for (int lvl = 0; lvl < 6; ++lvl) {
        const int res = 16 << lvl;
        const float px = c.x * (float)res;
        const float py = c.y * (float)res;
        const float fx = floorf(px), fy = floorf(py);
        const float wx = px - fx, wy = py - fy;
        const int ix = (int)fx, iy = (int)fy;
        const int stride = res + 1;
        const int base = ix + iy * stride;
        const float2* __restrict__ tl =
            reinterpret_cast<const float2*>(table) + (size_t)lvl * TSIZE;
        const float2 v00 = tl[base];
        const float2 v10 = tl[base + 1];
        const float2 v01 = tl[base + stride];
        const float2 v11 = tl[base + stride + 1];
        const float w00 = (1.0f - wx) * (1.0f - wy);
        const float w10 = wx * (1.0f - wy);
        const float w01 = (1.0f - wx) * wy;
        const float w11 = wx * wy;
        enc[2 * lvl]     = v00.x * w00 + v10.x * w10 + v01.x * w01 + v11.x * w11;
        enc[2 * lvl + 1] = v00.y * w00 + v10.y * w10 + v01.y * w01 + v11.y * w11;
    }
    #pragma unroll
    for (int l = 0; l < 6; ++l) {
        const float wx = hwx[l], wy = hwy[l];
        const float w00 = (1.0f - wx) * (1.0f - wy);
        const float w10 = wx * (1.0f - wy);
        const float w01 = (1.0f - wx) * wy;
        const float w11 = wx * wy;
        enc[2 * (l + 6)]     = hv00[l].x * w00 + hv10[l].x * w10 + hv01[l].x * w01 + hv11[l].x * w11;
        enc[2 * (l + 6) + 1] = hv00[l].y * w00 + hv10[l].y * w10 + hv01[l].y * w01 + hv11[l].y * w11;
    }

    float h0[16];
    #pragma unroll
    for (int j = 0; j < 16; ++j) {
        float aa = sb0[j];
        #pragma unroll
        for (int k = 0; k < 24; ++k) aa += enc[k] * sW0[k * 16 + j];
        h0[j] = __sinf(300.0f * aa);
    }
    float h1[16];
    #pragma unroll
    for (int j = 0; j < 16; ++j) {
        float aa = sb1[j];
        #pragma unroll
        for (int k = 0; k < 16; ++k) aa += h0[k] * sW1[k * 16 + j];
        h1[j] = __sinf(aa);
    }
    float h2[16];
    #pragma unroll
    for (int j = 0; j < 16; ++j) {
        float aa = sb2[j];
        #pragma unroll
        for (int k = 0; k < 16; ++k) aa += h1[k] * sW2[k * 16 + j];
        h2[j] = __sinf(aa);
    }
    float o = sb3;
    #pragma unroll
    for (int k = 0; k < 16; ++k) o += h2[k] * sW3[k];
    out[idx] = o;
}

extern "C" void kernel_launch(void* const* d_in, const int* in_sizes, int n_in,
                              void* d_out, int out_size, void* d_ws, size_t ws_size,
                              hipStream_t stream) {
    const float* coords = (const float*)d_in[0];
    const float* table  = (const float*)d_in[1];
    const float* W0 = (const float*)d_in[2];
    const float* b0 = (const float*)d_in[3];
    const float* W1 = (const float*)d_in[4];
    const float* b1 = (const float*)d_in[5];
    const float* W2 = (const float*)d_in[6];
    const float* b2 = (const float*)d_in[7];
    const float* W3 = (const float*)d_in[8];
    const float* b3 = (const float*)d_in[9];
    float* out = (float*)d_out;

    const int N = in_sizes[0] / 2;  // coords is [N,2]
    const int block = 256;
    const int grid = (N + block - 1) / block;

    const size_t need = (size_t)NHASH * TSIZE * 4u       // bf16 tables, 24 MiB
                      + (size_t)NHASH * (size_t)N * 4u;  // packed enc, 24 MiB
    if (ws_size >= need) {
        unsigned* wtab = (unsigned*)d_ws;
        unsigned* wenc = wtab + (size_t)NHASH * TSIZE;
        convert_kernel<<<4096, block, 0, stream>>>(table, wtab);
        for (int l = 0; l < NHASH; ++l)
            pass_kernel<<<grid, block, 0, stream>>>(coords, wtab, wenc, l, N);
        mlp_kernel<<<grid, block, 0, stream>>>(coords, table, wenc,
                                               W0, b0, W1, b1, W2, b2, W3, b3,
                                               out, N);
    } else {
        hashsiren_fused<<<grid, block, 0, stream>>>(coords, table,
                                                    W0, b0, W1, b1, W2, b2, W3, b3,
                                                    out, N);
    }
}